// Round 5
// baseline (222.768 us; speedup 1.0000x reference)
//
#include <hip/hip_runtime.h>
#include <hip/hip_bf16.h>

#define N_ENT    100000
#define NUM_REL  400
#define DIM      128
#define NUM_EDGES 800000
#define E_HALF   400000

using short8 = __attribute__((ext_vector_type(8))) short;
using f32x4  = __attribute__((ext_vector_type(4))) float;

__device__ __forceinline__ float bf_lo(unsigned u) { return __uint_as_float(u << 16); }
__device__ __forceinline__ float bf_hi(unsigned u) { return __uint_as_float(u & 0xffff0000u); }
__device__ __forceinline__ unsigned short f2bf(float f) {
    unsigned u = __float_as_uint(f);
    u = u + 0x7fffu + ((u >> 16) & 1u);   // RNE
    return (unsigned short)(u >> 16);
}
__device__ __forceinline__ unsigned pack2bf(float a, float b) {
    return (unsigned)f2bf(a) | ((unsigned)f2bf(b) << 16);
}

typedef const __attribute__((address_space(1))) void* gas_t;
typedef __attribute__((address_space(3))) void* las_t;
__device__ __forceinline__ void gll16(const void* g, void* l) {
    __builtin_amdgcn_global_load_lds((gas_t)g, (las_t)l, 16, 0, 0);
}

// ---------------- deg histogram ----------------
__global__ __launch_bounds__(256) void deg_kernel(const int* __restrict__ rows,
                                                  int* __restrict__ deg) {
    int e = blockIdx.x * 256 + threadIdx.x;
    if (e >= NUM_EDGES) return;
    int half = (e >= E_HALF) ? 1 : 0;
    atomicAdd(&deg[half * N_ENT + rows[e]], 1);
}

// ---------------- deg -> dinv ----------------
__global__ __launch_bounds__(256) void dinv_kernel(const int* __restrict__ deg,
                                                   float* __restrict__ dinv) {
    int i = blockIdx.x * 256 + threadIdx.x;
    if (i >= 2 * N_ENT) return;
    int d = deg[i];
    dinv[i] = (d > 0) ? rsqrtf((float)d) : 0.0f;
}

// ---------------- segment offsets via wave-atomic allocation ----------------
__global__ __launch_bounds__(256) void offs_kernel(const int* __restrict__ deg,
                                                   int* __restrict__ offs,
                                                   int* __restrict__ counter) {
    int i = blockIdx.x * 256 + threadIdx.x;
    int lane = threadIdx.x & 63;
    int v = (i < 2 * N_ENT) ? deg[i] : 0;
    int pre = v;
    #pragma unroll
    for (int d = 1; d < 64; d <<= 1) {
        int t = __shfl_up(pre, d);
        if (lane >= d) pre += t;
    }
    int total = __shfl(pre, 63);
    int base = 0;
    if (lane == 0) base = atomicAdd(counter, total);
    base = __shfl(base, 0);
    if (i < 2 * N_ENT) offs[i] = base + pre - v;
}

// ---------------- fill CSR records {col|t<<17, norm} ----------------
__global__ __launch_bounds__(256) void fill_kernel(const int* __restrict__ rows,
                                                   const int* __restrict__ cols,
                                                   const int* __restrict__ et,
                                                   const float* __restrict__ dinv,
                                                   const int* __restrict__ offs,
                                                   int* __restrict__ cursor,
                                                   uint2* __restrict__ recs) {
    int e = blockIdx.x * 256 + threadIdx.x;
    if (e >= NUM_EDGES) return;
    int half = (e >= E_HALF) ? 1 : 0;
    int g = half * N_ENT + rows[e];
    int col = cols[e];
    int t = et[e];
    int pos = atomicAdd(&cursor[g], 1);
    float norm = dinv[g] * dinv[half * N_ENT + col];
    recs[offs[g] + pos] = make_uint2((unsigned)col | ((unsigned)t << 17),
                                     __float_as_uint(norm));
}

// ---------------- prep: xl = bf16(x - loop_rel) ----------------
__global__ __launch_bounds__(256) void prep_x_kernel(const float4* __restrict__ x4,
                                                     const float4* __restrict__ loop4,
                                                     ushort4* __restrict__ xl4) {
    int i = blockIdx.x * 256 + threadIdx.x;
    if (i >= N_ENT * 32) return;
    float4 v = x4[i];
    float4 lr = loop4[i & 31];
    ushort4 o;
    o.x = f2bf(v.x - lr.x);
    o.y = f2bf(v.y - lr.y);
    o.z = f2bf(v.z - lr.z);
    o.w = f2bf(v.w - lr.w);
    xl4[i] = o;
}

// ---------------- prep: wt[n][384] = bf16 W^T concat ; rp = bf16(r - loop_rel) ----------------
__global__ __launch_bounds__(256) void prep_wr_kernel(const float* __restrict__ w_in,
                                                      const float* __restrict__ w_out,
                                                      const float* __restrict__ w_loop,
                                                      const float* __restrict__ r,
                                                      const float* __restrict__ loop_rel,
                                                      unsigned short* __restrict__ wt,
                                                      unsigned short* __restrict__ rp) {
    int i = blockIdx.x * 256 + threadIdx.x;
    if (i < 128 * 384) {
        int n = i / 384;
        int k = i % 384;
        int s = k >> 7;
        int kk = k & 127;
        const float* W = (s == 0) ? w_in : (s == 1) ? w_out : w_loop;
        wt[i] = f2bf(W[kk * DIM + n]);
    } else {
        int j = i - 128 * 384;
        if (j < NUM_REL * DIM)
            rp[j] = f2bf(r[j] - loop_rel[j & 127]);
    }
}

// ---------------- gather-aggregate: 16 lanes per (row,half), 4-edge unroll ----------------
#define ACC8(X, V, NRM)                                        \
    acc[0] += (NRM) * (bf_lo((X).x) - bf_lo((V).x));           \
    acc[1] += (NRM) * (bf_hi((X).x) - bf_hi((V).x));           \
    acc[2] += (NRM) * (bf_lo((X).y) - bf_lo((V).y));           \
    acc[3] += (NRM) * (bf_hi((X).y) - bf_hi((V).y));           \
    acc[4] += (NRM) * (bf_lo((X).z) - bf_lo((V).z));           \
    acc[5] += (NRM) * (bf_hi((X).z) - bf_hi((V).z));           \
    acc[6] += (NRM) * (bf_lo((X).w) - bf_lo((V).w));           \
    acc[7] += (NRM) * (bf_hi((X).w) - bf_hi((V).w));

__global__ __launch_bounds__(256) void gather_agg_kernel(const int* __restrict__ offs,
                                                         const int* __restrict__ deg,
                                                         const uint2* __restrict__ recs,
                                                         const unsigned short* __restrict__ xl,
                                                         const unsigned short* __restrict__ rp,
                                                         unsigned short* __restrict__ agg) {
    int gid = blockIdx.x * 256 + threadIdx.x;
    int g = gid >> 4;
    if (g >= 2 * N_ENT) return;
    int c = gid & 15;                    // lane covers 16 B = 8 bf16
    int e = offs[g];
    int end = e + deg[g];
    float acc[8] = {0.f, 0.f, 0.f, 0.f, 0.f, 0.f, 0.f, 0.f};
    for (; e + 4 <= end; e += 4) {
        uint2 r0 = recs[e];
        uint2 r1 = recs[e + 1];
        uint2 r2 = recs[e + 2];
        uint2 r3 = recs[e + 3];
        uint4 x0 = ((const uint4*)(xl + (size_t)(r0.x & 0x1ffff) * DIM))[c];
        uint4 v0 = ((const uint4*)(rp + (size_t)(r0.x >> 17) * DIM))[c];
        uint4 x1 = ((const uint4*)(xl + (size_t)(r1.x & 0x1ffff) * DIM))[c];
        uint4 v1 = ((const uint4*)(rp + (size_t)(r1.x >> 17) * DIM))[c];
        uint4 x2 = ((const uint4*)(xl + (size_t)(r2.x & 0x1ffff) * DIM))[c];
        uint4 v2 = ((const uint4*)(rp + (size_t)(r2.x >> 17) * DIM))[c];
        uint4 x3 = ((const uint4*)(xl + (size_t)(r3.x & 0x1ffff) * DIM))[c];
        uint4 v3 = ((const uint4*)(rp + (size_t)(r3.x >> 17) * DIM))[c];
        float n0 = __uint_as_float(r0.y);
        float n1 = __uint_as_float(r1.y);
        float n2 = __uint_as_float(r2.y);
        float n3 = __uint_as_float(r3.y);
        ACC8(x0, v0, n0)
        ACC8(x1, v1, n1)
        ACC8(x2, v2, n2)
        ACC8(x3, v3, n3)
    }
    for (; e < end; ++e) {
        uint2 rA = recs[e];
        uint4 xA = ((const uint4*)(xl + (size_t)(rA.x & 0x1ffff) * DIM))[c];
        uint4 vA = ((const uint4*)(rp + (size_t)(rA.x >> 17) * DIM))[c];
        float nA = __uint_as_float(rA.y);
        ACC8(xA, vA, nA)
    }
    uint4 o;
    o.x = pack2bf(acc[0], acc[1]);
    o.y = pack2bf(acc[2], acc[3]);
    o.z = pack2bf(acc[4], acc[5]);
    o.w = pack2bf(acc[6], acc[7]);
    ((uint4*)(agg + (size_t)g * DIM))[c] = o;
}

// ---------------- MFMA GEMM, double-buffered 2-phase (T3-min) + T2 source swizzle ----------------
// out = tanh(([aggA|aggB|xl] @ Wcat)/3 + bias). M=100000, N=128, K=384.
// 128 rows/block, 4 waves 2x2 (64x64 each), BK=64, 6 K-steps, prefetch-before-compute.
__global__ __launch_bounds__(256) void mfma_gemm_kernel(const unsigned short* __restrict__ aggA,
                                                        const unsigned short* __restrict__ aggB,
                                                        const unsigned short* __restrict__ xl,
                                                        const unsigned short* __restrict__ wt,
                                                        const float* __restrict__ bias,
                                                        float* __restrict__ out) {
    __shared__ char smem[65536];        // [buf][A 16K | B 16K]

    int tid = threadIdx.x;
    int wave = tid >> 6;
    int lane = tid & 63;
    int wm = wave >> 1, wn = wave & 1;
    int row0 = blockIdx.x * 128;
    int lr = lane & 15;
    int lkb = (lane >> 4) * 16;          // frag k byte offset within 64B mfma slice

    // staging decomposition: 64 lanes = 8 rows x 8 chunks of 16B
    int sr  = lane >> 3;                               // 0..7 row within chunk
    int ssb = ((lane & 7) << 4) ^ (sr << 4);           // swizzled source byte in 128B slice

    const unsigned short* Asrc[3] = {aggA, aggB, xl};

    f32x4 acc[4][4];
    #pragma unroll
    for (int mi = 0; mi < 4; ++mi)
        #pragma unroll
        for (int ni = 0; ni < 4; ++ni)
            acc[mi][ni] = (f32x4){0.f, 0.f, 0.f, 0.f};

    // ---- STAGE(buf, step): issue 8 gll16 (no waits) ----
    auto STAGE = [&](int buf, int step) {
        int s = step >> 1;
        int k0b = (step & 1) * 128;                    // byte offset within 256B source row
        const char* Ab = (const char*)Asrc[s];
        const char* Bb = (const char*)wt + s * 256 + k0b;   // wt row stride 768B
        char* Abase = smem + buf * 32768;
        char* Bbase = Abase + 16384;
        #pragma unroll
        for (int j = 0; j < 4; ++j) {
            int rl = wave * 32 + j * 8;                // uniform per instruction
            int grow = row0 + rl + sr;
            if (grow > N_ENT - 1) grow = N_ENT - 1;
            gll16(Ab + (size_t)grow * 256 + k0b + ssb, Abase + rl * 128);
        }
        #pragma unroll
        for (int j = 0; j < 4; ++j) {
            int nl = wave * 32 + j * 8;
            gll16(Bb + (size_t)(nl + sr) * 768 + ssb, Bbase + nl * 128);
        }
    };

    // ---- prologue ----
    STAGE(0, 0);
    __syncthreads();                                   // drain prologue loads

    for (int step = 0; step < 6; ++step) {
        int cur = step & 1;
        if (step < 5) STAGE(cur ^ 1, step + 1);        // issue next-tile loads

        const char* Abase = smem + cur * 32768;
        const char* Bbase = Abase + 16384;
        #pragma unroll
        for (int kk = 0; kk < 2; ++kk) {
            int kb = kk * 64 + lkb;                    // 16B-aligned byte in [0,128)
            short8 a[4], b[4];
            #pragma unroll
            for (int mi = 0; mi < 4; ++mi) {
                int ar = wm * 64 + mi * 16 + lr;
                a[mi] = *(const short8*)(Abase + ar * 128 + (kb ^ ((ar & 7) << 4)));
            }
            #pragma unroll
            for (int ni = 0; ni < 4; ++ni) {
                int bn = wn * 64 + ni * 16 + lr;
                b[ni] = *(const short8*)(Bbase + bn * 128 + (kb ^ ((bn & 7) << 4)));
            }
            #pragma unroll
            for (int mi = 0; mi < 4; ++mi)
                #pragma unroll
                for (int ni = 0; ni < 4; ++ni)
                    acc[mi][ni] = __builtin_amdgcn_mfma_f32_16x16x32_bf16(a[mi], b[ni], acc[mi][ni], 0, 0, 0);
        }
        if (step < 5) __syncthreads();                 // drain next-tile loads + consumption fence
    }

    int col0 = wn * 64;
    int row0w = row0 + wm * 64;
    const float third = 1.0f / 3.0f;
    float bb[4];
    #pragma unroll
    for (int ni = 0; ni < 4; ++ni) bb[ni] = bias[col0 + ni * 16 + lr];

    #pragma unroll
    for (int mi = 0; mi < 4; ++mi) {
        #pragma unroll
        for (int reg = 0; reg < 4; ++reg) {
            int grow = row0w + mi * 16 + (lane >> 4) * 4 + reg;
            if (grow < N_ENT) {
                #pragma unroll
                for (int ni = 0; ni < 4; ++ni)
                    out[(size_t)grow * DIM + col0 + ni * 16 + lr] =
                        tanhf(acc[mi][ni][reg] * third + bb[ni]);
            }
        }
    }
}

// ---------------- r_out = r @ w_rel  (400x128 @ 128x128, f32) ----------------
__global__ __launch_bounds__(128) void rel_gemm_kernel(const float* __restrict__ r,
                                                       const float* __restrict__ w_rel,
                                                       float* __restrict__ r_out) {
    __shared__ float rrow[128];
    int i = blockIdx.x;
    int j = threadIdx.x;
    rrow[j] = r[i * DIM + j];
    __syncthreads();
    float acc = 0.0f;
    #pragma unroll 8
    for (int k = 0; k < DIM; ++k)
        acc += rrow[k] * w_rel[k * DIM + j];
    r_out[i * DIM + j] = acc;
}

extern "C" void kernel_launch(void* const* d_in, const int* in_sizes, int n_in,
                              void* d_out, int out_size, void* d_ws, size_t ws_size,
                              hipStream_t stream) {
    const float* x        = (const float*)d_in[0];
    const float* r        = (const float*)d_in[1];
    const int*   ei       = (const int*)d_in[2];   // [2][800000]: rows then cols
    const int*   et       = (const int*)d_in[3];
    const float* w_in     = (const float*)d_in[4];
    const float* w_out    = (const float*)d_in[5];
    const float* w_loop   = (const float*)d_in[6];
    const float* w_rel    = (const float*)d_in[7];
    const float* loop_rel = (const float*)d_in[8];
    const float* bias     = (const float*)d_in[9];

    float* out   = (float*)d_out;            // 100000*128
    float* r_out = out + (size_t)N_ENT * DIM;

    // -------- workspace layout --------
    unsigned short* agg = (unsigned short*)d_ws;            // [2N][128] bf16 (in | out)
    unsigned short* xl  = agg + 2ull * N_ENT * DIM;         // [N][128] bf16
    unsigned short* wt  = xl + (size_t)N_ENT * DIM;         // [128][384] bf16
    unsigned short* rp  = wt + 128 * 384;                   // [400][128] bf16
    uint2* recs = (uint2*)(rp + NUM_REL * DIM);             // 800k x 8 B
    int*   deg     = (int*)(recs + NUM_EDGES);              // 2N
    int*   cursor  = deg + 2 * N_ENT;                       // 2N
    int*   counter = cursor + 2 * N_ENT;                    // 1 (+3 pad)
    int*   offs    = counter + 4;                           // 2N
    float* dinv    = (float*)(offs + 2 * N_ENT);            // 2N

    const int* rows = ei;
    const int* cols = ei + NUM_EDGES;

    hipMemsetAsync(deg, 0, (4ull * N_ENT + 4) * sizeof(int), stream);

    deg_kernel<<<(NUM_EDGES + 255) / 256, 256, 0, stream>>>(rows, deg);
    dinv_kernel<<<(2 * N_ENT + 255) / 256, 256, 0, stream>>>(deg, dinv);
    offs_kernel<<<(2 * N_ENT + 255) / 256, 256, 0, stream>>>(deg, offs, counter);
    fill_kernel<<<(NUM_EDGES + 255) / 256, 256, 0, stream>>>(rows, cols, et, dinv, offs, cursor, recs);

    prep_x_kernel<<<(N_ENT * 32 + 255) / 256, 256, 0, stream>>>(
        (const float4*)x, (const float4*)loop_rel, (ushort4*)xl);
    prep_wr_kernel<<<(128 * 384 + NUM_REL * DIM + 255) / 256, 256, 0, stream>>>(
        w_in, w_out, w_loop, r, loop_rel, wt, rp);

    gather_agg_kernel<<<(2 * N_ENT * 16 + 255) / 256, 256, 0, stream>>>(
        offs, deg, recs, xl, rp, agg);

    mfma_gemm_kernel<<<(N_ENT + 127) / 128, 256, 0, stream>>>(
        agg, agg + (size_t)N_ENT * DIM, xl, wt, bias, out);

    rel_gemm_kernel<<<NUM_REL, 128, 0, stream>>>(r, w_rel, r_out);
}